// Round 3
// baseline (498.102 us; speedup 1.0000x reference)
//
#include <hip/hip_runtime.h>
#include <math.h>

#define T_ 256
#define B_ 128
#define D_ 1024
#define K_ 21
#define TK (T_ * K_)  // 5376

// ---------------------------------------------------------------------------
// Kernel 1: FC projection. One wave (64 lanes) per block; lane = row.
// CRITICAL: the d-loop is block-uniform (no threadIdx in W addressing) so the
// compiler proves W loads uniform -> s_load scalar broadcast (round-2 bug:
// wave-split d0 made W divergent -> 10k per-lane VMEM loads).
// Output layout fc[b][t][k] (batch-contiguous) for coalesced scan staging.
// ---------------------------------------------------------------------------
__global__ __launch_bounds__(64) void fc_kernel(
    const float* __restrict__ A, const float* __restrict__ W,
    const float* __restrict__ bias, float* __restrict__ fc) {
  const int lane = threadIdx.x;
  const int row = blockIdx.x * 64 + lane;  // row = t*B_ + b
  const int t = row >> 7;                  // / B_
  const int b = row & (B_ - 1);
  const float* Arow = A + (size_t)row * D_;

  float acc[K_];
#pragma unroll
  for (int k = 0; k < K_; ++k) acc[k] = 0.f;

  for (int d = 0; d < D_; d += 4) {  // d uniform -> W+d*K_ uniform -> s_load
    const float4 a4 = *(const float4*)(Arow + d);
    const float* Wp = W + d * K_;
#pragma unroll
    for (int k = 0; k < K_; ++k) {
      acc[k] = fmaf(a4.x, Wp[k], acc[k]);
      acc[k] = fmaf(a4.y, Wp[K_ + k], acc[k]);
      acc[k] = fmaf(a4.z, Wp[2 * K_ + k], acc[k]);
      acc[k] = fmaf(a4.w, Wp[3 * K_ + k], acc[k]);
    }
  }

  float* o = fc + ((size_t)b * T_ + t) * K_;
#pragma unroll
  for (int k = 0; k < K_; ++k) o[k] = acc[k] + bias[k];
}

// ---------------------------------------------------------------------------
// Kernel 2: all sequential work, one wave per block.
//   blocks [0,128):   forward (denominator), linear domain w/ renorm
//   blocks [128,256): Viterbi + 2-level skip-list backtrack
//   blocks [256,384): numerator (gold-path score)
// Emissions staged into LDS coalesced (fc is [b][t][k]); recurrence runs out
// of LDS with one-step register prefetch. Loss accumulated into d_out slot.
// ---------------------------------------------------------------------------
__global__ __launch_bounds__(64) void scan_kernel(
    const float* __restrict__ fc, const int* __restrict__ tags,
    const float* __restrict__ startT, const float* __restrict__ endT,
    const float* __restrict__ trans, float* __restrict__ out_tags,
    float* __restrict__ out_loss) {
  __shared__ __align__(16) float es[TK + 32];  // emissions (exp'd for fwd)
  __shared__ int msk[T_ + 8];                  // raw tags (mask = !=0)
  __shared__ unsigned char h1[256][24];        // fine backptrs (step t-1)
  __shared__ unsigned char h2[128][24];        // composed: tag@t -> tag@(t-2)
  __shared__ unsigned char curarr[256];        // decoded path

  const int lane = threadIdx.x;
  const int jc = lane < K_ ? lane : K_ - 1;

  if (blockIdx.x < 2 * B_) {
    const bool fwd = blockIdx.x < B_;
    const int b = fwd ? blockIdx.x : blockIdx.x - B_;

    // ---- stage emissions + tags into LDS (coalesced) ----
    const float* src = fc + (size_t)b * TK;
#pragma unroll
    for (int i = 0; i < TK / 256; ++i) {  // 21 iters of float4
      const int f = i * 64 + lane;
      float4 v = *(const float4*)(src + 4 * f);
      if (fwd) {
        v.x = __expf(v.x); v.y = __expf(v.y);
        v.z = __expf(v.z); v.w = __expf(v.w);
      }
      *(float4*)(es + 4 * f) = v;
    }
#pragma unroll
    for (int q = 0; q < 4; ++q) {
      const int t = q * 64 + lane;
      msk[t] = tags[t * B_ + b];
    }
    __syncthreads();

    if (fwd) {
      // ---------------- forward / denominator ----------------
      float etcol[K_];
#pragma unroll
      for (int i = 0; i < K_; ++i) etcol[i] = __expf(trans[i * K_ + jc]);

      float p = __expf(startT[jc]) * es[jc];
      float L = 0.f;
      float e_nxt = es[K_ + jc];
      int m_nxt = msk[1];

      for (int t = 1; t < T_; ++t) {
        const float eet = e_nxt;
        const int mt = m_nxt;
        e_nxt = es[(t + 1) * K_ + jc];  // padded: safe at t=255
        m_nxt = msk[t + 1];
        float s[K_];
#pragma unroll
        for (int i = 0; i < K_; ++i) s[i] = __shfl(p, i, 64);
        float dA = 0.f, dB = 0.f, dC = 0.f, SA = 0.f, SB = 0.f, SC = 0.f;
#pragma unroll
        for (int i = 0; i < K_; i += 3) {
          dA = fmaf(s[i], etcol[i], dA);
          dB = fmaf(s[i + 1], etcol[i + 1], dB);
          dC = fmaf(s[i + 2], etcol[i + 2], dC);
          SA += s[i];
          SB += s[i + 1];
          SC += s[i + 2];
        }
        const float S = SA + SB + SC;
        const float dot = dA + dB + dC;
        const float pn = dot * __builtin_amdgcn_rcpf(S) * eet;
        p = mt ? pn : p;
        L += mt ? __logf(S) : 0.f;
      }
      const float w = p * __expf(endT[jc]);
      float tot = 0.f;
#pragma unroll
      for (int i = 0; i < K_; ++i) tot += __shfl(w, i, 64);
      if (lane == 0) atomicAdd(out_loss, L + __logf(tot));  // +den
    } else {
      // ---------------- Viterbi ----------------
      float tcol[K_];
#pragma unroll
      for (int i = 0; i < K_; ++i) tcol[i] = trans[i * K_ + jc];

      float sc = startT[jc] + es[jc];
      float e_nxt = es[K_ + jc];
      int m_nxt = msk[1];
      int prev_ptr = jc;

      for (int t = 1; t < T_; ++t) {
        const float emt = e_nxt;
        const int mt = m_nxt;
        e_nxt = es[(t + 1) * K_ + jc];
        m_nxt = msk[t + 1];
        float s[K_], c[K_];
#pragma unroll
        for (int i = 0; i < K_; ++i) s[i] = __shfl(sc, i, 64);
#pragma unroll
        for (int i = 0; i < K_; ++i) c[i] = s[i] + tcol[i];
        float mA = c[0], mB = c[1], mC = c[2];
#pragma unroll
        for (int i = 3; i < K_; i += 3) {
          mA = fmaxf(mA, c[i]);
          mB = fmaxf(mB, c[i + 1]);
          mC = fmaxf(mC, c[i + 2]);
        }
        const float mx = fmaxf(mA, fmaxf(mB, mC));
        int idx = 0;
#pragma unroll
        for (int i = K_ - 1; i >= 0; --i) idx = (c[i] == mx) ? i : idx;
        const int ptr = mt ? idx : jc;
        sc = mt ? (mx + emt) : sc;
        if (lane < K_) h1[t - 1][lane] = (unsigned char)ptr;
        if ((t & 1) == 0) {
          // compose: tag@t -ptr-> tag@(t-1) -prev_ptr-> tag@(t-2), off-path
          const int comp = __shfl(prev_ptr, ptr, 64);
          if (lane < K_) h2[(t - 2) >> 1][lane] = (unsigned char)comp;
        }
        prev_ptr = ptr;
      }
      __syncthreads();

      const float fin = sc + endT[jc];
      float s[K_];
#pragma unroll
      for (int i = 0; i < K_; ++i) s[i] = __shfl(fin, i, 64);
      float mA = s[0], mB = s[1], mC = s[2];
#pragma unroll
      for (int i = 3; i < K_; i += 3) {
        mA = fmaxf(mA, s[i]);
        mB = fmaxf(mB, s[i + 1]);
        mC = fmaxf(mC, s[i + 2]);
      }
      const float mx = fmaxf(mA, fmaxf(mB, mC));
      int last = 0;
#pragma unroll
      for (int i = K_ - 1; i >= 0; --i) last = (s[i] == mx) ? i : last;

      if (lane == 0) {
        int cur = last;  // tag at t=255
        curarr[255] = (unsigned char)cur;
        cur = h1[254][cur];  // tag at t=254
        curarr[254] = (unsigned char)cur;
        for (int t = 254; t >= 2; t -= 2) {  // 127 dependent u8 reads
          cur = h2[(t - 2) >> 1][cur];
          curarr[t - 2] = (unsigned char)cur;
        }
      }
      __syncthreads();
      // odd positions in parallel: cur_u = h1[u][cur_{u+1}]
#pragma unroll
      for (int r = 0; r < 2; ++r) {
        const int u = 2 * (lane + 64 * r) + 1;
        if (u < 255) curarr[u] = h1[u][curarr[u + 1]];
      }
      __syncthreads();
#pragma unroll
      for (int q = 0; q < 4; ++q) {
        const int t = q * 64 + lane;
        out_tags[t * B_ + b] = (msk[t] != 0) ? (float)curarr[t] : 0.f;
      }
    }
  } else {
    // ---------------- numerator ----------------
    const int b = blockIdx.x - 2 * B_;
    const float* fcb = fc + (size_t)b * TK;
    float contrib = 0.f;
#pragma unroll
    for (int q = 0; q < 4; ++q) {
      const int t = lane * 4 + q;
      const int tg = tags[t * B_ + b];
      if (t == 0) {
        contrib += startT[tg] + fcb[tg];
      } else if (tg != 0) {
        const int pg = tags[(t - 1) * B_ + b];
        contrib += trans[pg * K_ + tg] + fcb[t * K_ + tg];
      }
      const bool isLast =
          (tg != 0) && (t == T_ - 1 || tags[(t + 1) * B_ + b] == 0);
      if (isLast) contrib += endT[tg];
    }
#pragma unroll
    for (int off = 32; off > 0; off >>= 1)
      contrib += __shfl_down(contrib, off, 64);
    if (lane == 0) atomicAdd(out_loss, -contrib);  // -num
  }
}

extern "C" void kernel_launch(void* const* d_in, const int* in_sizes, int n_in,
                              void* d_out, int out_size, void* d_ws,
                              size_t ws_size, hipStream_t stream) {
  const float* A = (const float*)d_in[0];       // (T,B,D) f32
  const int* tags = (const int*)d_in[1];        // (T,B) i32
  const float* W = (const float*)d_in[2];       // (D,K) f32
  const float* bias = (const float*)d_in[3];    // (K,)
  const float* startT = (const float*)d_in[4];  // (K,)
  const float* endT = (const float*)d_in[5];    // (K,)
  const float* trans = (const float*)d_in[6];   // (K,K)

  float* out_tags = (float*)d_out;                    // (T,B) as f32
  float* out_loss = (float*)d_out + (size_t)T_ * B_;  // scalar slot

  float* fc = (float*)d_ws;  // [b][t][k], T*B*K f32

  hipMemsetAsync(out_loss, 0, sizeof(float), stream);
  fc_kernel<<<(T_ * B_) / 64, 64, 0, stream>>>(A, W, bias, fc);
  scan_kernel<<<3 * B_, 64, 0, stream>>>(fc, tags, startT, endT, trans,
                                         out_tags, out_loss);
}

// Round 4
// 341.349 us; speedup vs baseline: 1.4592x; 1.4592x over previous
//
#include <hip/hip_runtime.h>
#include <math.h>

#define T_ 256
#define B_ 128
#define D_ 1024
#define K_ 21
#define NCH 2                 // d-split chunks (ws = NCH * 2.75 MB, proven safe)
#define PR (T_ * B_ * K_)     // per-chunk partial element count

#define REP21(X) X(0) X(1) X(2) X(3) X(4) X(5) X(6) X(7) X(8) X(9) X(10) \
                 X(11) X(12) X(13) X(14) X(15) X(16) X(17) X(18) X(19) X(20)

// ---------------------------------------------------------------------------
// Kernel 1: FC projection, partials. Grid (512, 2), block 128 (2 waves).
// Block (rb,c): rows rb*64..+63 (lane-mapped), d-chunk c*512..+511 split
// 256/wave. W delivered via explicit float4 VMEM loads (wave-uniform address
// -> 1 fetch/wave, broadcast by the memory system; ~25 VMEM per 84 FMA).
// Everything manually unrolled — no scalar-indexed arrays for the compiler
// to demote (round-3 failure mode). Bias folded into chunk-0 init.
// ---------------------------------------------------------------------------
__device__ __forceinline__ void fma21(float a, const float* __restrict__ Wd,
                                      float* __restrict__ acc) {
  const float4 w0 = *(const float4*)(Wd);
  const float4 w1 = *(const float4*)(Wd + 4);
  const float4 w2 = *(const float4*)(Wd + 8);
  const float4 w3 = *(const float4*)(Wd + 12);
  const float4 w4 = *(const float4*)(Wd + 16);
  const float w20 = Wd[20];
  acc[0] = fmaf(a, w0.x, acc[0]);   acc[1] = fmaf(a, w0.y, acc[1]);
  acc[2] = fmaf(a, w0.z, acc[2]);   acc[3] = fmaf(a, w0.w, acc[3]);
  acc[4] = fmaf(a, w1.x, acc[4]);   acc[5] = fmaf(a, w1.y, acc[5]);
  acc[6] = fmaf(a, w1.z, acc[6]);   acc[7] = fmaf(a, w1.w, acc[7]);
  acc[8] = fmaf(a, w2.x, acc[8]);   acc[9] = fmaf(a, w2.y, acc[9]);
  acc[10] = fmaf(a, w2.z, acc[10]); acc[11] = fmaf(a, w2.w, acc[11]);
  acc[12] = fmaf(a, w3.x, acc[12]); acc[13] = fmaf(a, w3.y, acc[13]);
  acc[14] = fmaf(a, w3.z, acc[14]); acc[15] = fmaf(a, w3.w, acc[15]);
  acc[16] = fmaf(a, w4.x, acc[16]); acc[17] = fmaf(a, w4.y, acc[17]);
  acc[18] = fmaf(a, w4.z, acc[18]); acc[19] = fmaf(a, w4.w, acc[19]);
  acc[20] = fmaf(a, w20, acc[20]);
}

__global__ __launch_bounds__(128) void fc_kernel(
    const float* __restrict__ A, const float* __restrict__ W,
    const float* __restrict__ bias, float* __restrict__ P) {
  __shared__ float red[64][23];
  const int lane = threadIdx.x & 63;
  const int wv = threadIdx.x >> 6;
  const int rb = blockIdx.x;  // 0..511
  const int c = blockIdx.y;   // 0..1
  const int r = rb * 64 + lane;

  const float* Arow = A + (size_t)r * D_ + c * 512 + wv * 256;
  const float* Wc = W + (c * 512 + wv * 256) * K_;

  float acc[K_];
  if (c == 0 && wv == 0) {
#pragma unroll
    for (int k = 0; k < K_; ++k) acc[k] = bias[k];
  } else {
#pragma unroll
    for (int k = 0; k < K_; ++k) acc[k] = 0.f;
  }

  for (int g = 0; g < 64; ++g) {
    const float4 a4 = *(const float4*)(Arow + 4 * g);
    const float* Wp = Wc + 4 * g * K_;
    fma21(a4.x, Wp, acc);
    fma21(a4.y, Wp + K_, acc);
    fma21(a4.z, Wp + 2 * K_, acc);
    fma21(a4.w, Wp + 3 * K_, acc);
  }

  if (wv == 1) {
#pragma unroll
    for (int k = 0; k < K_; ++k) red[lane][k] = acc[k];
  }
  __syncthreads();
  if (wv == 0) {
#pragma unroll
    for (int k = 0; k < K_; ++k) acc[k] += red[lane][k];
    float* o = P + (size_t)c * PR + (size_t)r * K_;
    *(float4*)(o) = make_float4(acc[0], acc[1], acc[2], acc[3]);
    *(float4*)(o + 4) = make_float4(acc[4], acc[5], acc[6], acc[7]);
    *(float4*)(o + 8) = make_float4(acc[8], acc[9], acc[10], acc[11]);
    *(float4*)(o + 12) = make_float4(acc[12], acc[13], acc[14], acc[15]);
    *(float4*)(o + 16) = make_float4(acc[16], acc[17], acc[18], acc[19]);
    o[20] = acc[20];
  }
}

// ---------------------------------------------------------------------------
// Kernel 2: sequential scans, one wave per block.
//   [0,128): forward/denominator — linear domain, renorm every 8 steps,
//            cross-lane broadcast via v_readlane (VALU) not ds_bpermute.
//   [128,256): Viterbi — packed int argmax keys, post-loop h2/h4 skiplists.
//   [256,384): numerator.
// ---------------------------------------------------------------------------
__global__ __launch_bounds__(64) void scan_kernel(
    const float* __restrict__ P, const int* __restrict__ tags,
    const float* __restrict__ startT, const float* __restrict__ endT,
    const float* __restrict__ trans, float* __restrict__ out_tags,
    float* __restrict__ out_loss) {
  __shared__ __align__(16) float es[T_ * 24 + 32];  // emission rows, stride 24
  __shared__ int msk[T_ + 8];
  __shared__ unsigned char bp[256][24];  // bp[t][tag@t] = tag@(t-1), t>=1
  __shared__ unsigned char h2[127][24];  // tag@(2v) from tag@(2v+2)
  __shared__ unsigned char h4[63][24];   // tag@(4w) from tag@(4w+4)
  __shared__ unsigned char curarr[256];

  const int lane = threadIdx.x;
  const int jc = lane < K_ ? lane : K_ - 1;

  if (blockIdx.x < 2 * B_) {
    const bool fwd = blockIdx.x < B_;
    const int b = fwd ? blockIdx.x : blockIdx.x - B_;

    // ---- stage emissions (sum both partials) + tags ----
    const float* p0 = P + (size_t)b * K_;  // row (t,b) at offset (t*B_+b)*21
#pragma unroll
    for (int q = 0; q < 4; ++q) {
      const int t = q * 64 + lane;
      const float* r0 = p0 + (size_t)t * B_ * K_;
      const float* r1 = r0 + PR;
      float4 v0 = *(const float4*)(r0);
      float4 v1 = *(const float4*)(r0 + 4);
      float4 v2 = *(const float4*)(r0 + 8);
      float4 v3 = *(const float4*)(r0 + 12);
      float4 v4 = *(const float4*)(r0 + 16);
      float v5 = r0[20];
      const float4 u0 = *(const float4*)(r1);
      const float4 u1 = *(const float4*)(r1 + 4);
      const float4 u2 = *(const float4*)(r1 + 8);
      const float4 u3 = *(const float4*)(r1 + 12);
      const float4 u4 = *(const float4*)(r1 + 16);
      const float u5 = r1[20];
      v0.x += u0.x; v0.y += u0.y; v0.z += u0.z; v0.w += u0.w;
      v1.x += u1.x; v1.y += u1.y; v1.z += u1.z; v1.w += u1.w;
      v2.x += u2.x; v2.y += u2.y; v2.z += u2.z; v2.w += u2.w;
      v3.x += u3.x; v3.y += u3.y; v3.z += u3.z; v3.w += u3.w;
      v4.x += u4.x; v4.y += u4.y; v4.z += u4.z; v4.w += u4.w;
      v5 += u5;
      if (fwd) {
        v0.x = __expf(v0.x); v0.y = __expf(v0.y); v0.z = __expf(v0.z); v0.w = __expf(v0.w);
        v1.x = __expf(v1.x); v1.y = __expf(v1.y); v1.z = __expf(v1.z); v1.w = __expf(v1.w);
        v2.x = __expf(v2.x); v2.y = __expf(v2.y); v2.z = __expf(v2.z); v2.w = __expf(v2.w);
        v3.x = __expf(v3.x); v3.y = __expf(v3.y); v3.z = __expf(v3.z); v3.w = __expf(v3.w);
        v4.x = __expf(v4.x); v4.y = __expf(v4.y); v4.z = __expf(v4.z); v4.w = __expf(v4.w);
        v5 = __expf(v5);
      }
      float* er = es + t * 24;
      *(float4*)(er) = v0;      *(float4*)(er + 4) = v1;
      *(float4*)(er + 8) = v2;  *(float4*)(er + 12) = v3;
      *(float4*)(er + 16) = v4; er[20] = v5;
      msk[t] = tags[t * B_ + b];
    }
    __syncthreads();

    float s[K_];
#define RDL_P(i) s[i] = __uint_as_float((unsigned)__builtin_amdgcn_readlane((int)__float_as_uint(p), i));
#define RDL_SC(i) s[i] = __uint_as_float((unsigned)__builtin_amdgcn_readlane((int)__float_as_uint(sc), i));

    if (fwd) {
      // ---------------- forward / denominator ----------------
      float etcol[K_];
#pragma unroll
      for (int i = 0; i < K_; ++i) etcol[i] = __expf(trans[i * K_ + jc]);

      float p = __expf(startT[jc]) * es[jc];
      float L = 0.f;
      float e_nxt = es[24 + jc];
      int m_nxt = msk[1];

      for (int t = 1; t < T_; ++t) {
        const float eet = e_nxt;
        const int mt = m_nxt;
        e_nxt = es[(t + 1) * 24 + jc];
        m_nxt = msk[t + 1];
        REP21(RDL_P)
        float dA = s[0] * etcol[0];
        float dB = s[1] * etcol[1];
        float dC = s[2] * etcol[2];
#pragma unroll
        for (int i = 3; i < K_; i += 3) {
          dA = fmaf(s[i], etcol[i], dA);
          dB = fmaf(s[i + 1], etcol[i + 1], dB);
          dC = fmaf(s[i + 2], etcol[i + 2], dC);
        }
        const float pn = (dA + dB + dC) * eet;
        if ((t & 7) == 0) {  // periodic renorm (f32-range-safe between)
          float SA = s[0], SB = s[1], SC = s[2];
#pragma unroll
          for (int i = 3; i < K_; i += 3) {
            SA += s[i]; SB += s[i + 1]; SC += s[i + 2];
          }
          const float S = SA + SB + SC;
          p = (mt ? pn : p) * __builtin_amdgcn_rcpf(S);
          L += __logf(S);
        } else {
          p = mt ? pn : p;
        }
      }
      const float w = p * __expf(endT[jc]);
      float sc = w;  // reuse readlane macro
      REP21(RDL_SC)
      float SA = s[0], SB = s[1], SC = s[2];
#pragma unroll
      for (int i = 3; i < K_; i += 3) { SA += s[i]; SB += s[i + 1]; SC += s[i + 2]; }
      if (lane == 0) atomicAdd(out_loss, L + __logf(SA + SB + SC));  // +den
    } else {
      // ---------------- Viterbi ----------------
      float tcolb[K_];
#pragma unroll
      for (int i = 0; i < K_; ++i) tcolb[i] = trans[i * K_ + jc] + 2048.0f;

      float sc = startT[jc] + es[jc];
      float e_nxt = es[24 + jc];
      int m_nxt = msk[1];

      for (int t = 1; t < T_; ++t) {
        const float emt = e_nxt;
        const int mt = m_nxt;
        e_nxt = es[(t + 1) * 24 + jc];
        m_nxt = msk[t + 1];
        REP21(RDL_SC)
        // packed keys: high bits = biased-positive score, low 5 = 20-i
        int kA = 0, kB = 0, kC = 0;
#define VKEY(i)                                                              \
        {                                                                    \
          const float ci = s[i] + tcolb[i];                                  \
          const int ki = (__float_as_int(ci) & 0xFFFFFFE0) | (20 - i);       \
          if (i == 0) kA = ki;                                               \
          else if (i == 1) kB = ki;                                          \
          else if (i == 2) kC = ki;                                          \
          else if ((i) % 3 == 0) kA = kA > ki ? kA : ki;                     \
          else if ((i) % 3 == 1) kB = kB > ki ? kB : ki;                     \
          else kC = kC > ki ? kC : ki;                                       \
        }
        REP21(VKEY)
#undef VKEY
        int key = kA > kB ? kA : kB;
        key = key > kC ? key : kC;
        const int idx = 20 - (key & 31);
        const float mval = __int_as_float(key & 0xFFFFFFE0) - 2048.0f;
        sc = mt ? (mval + emt) : sc;
        const int ptr = mt ? idx : jc;
        if (lane < K_) bp[t][lane] = (unsigned char)ptr;
      }
      __syncthreads();

      // final argmax over lanes via packed keys + readlane
      const float finb = sc + endT[jc] + 2048.0f;
      const int myk = (__float_as_int(finb) & 0xFFFFFFE0) | (20 - jc);
      int kmax = 0;
#define RDK(i)                                                               \
      {                                                                      \
        const int ki = __builtin_amdgcn_readlane(myk, i);                    \
        kmax = (i == 0) ? ki : (kmax > ki ? kmax : ki);                      \
      }
      REP21(RDK)
#undef RDK
      const int last = 20 - (kmax & 31);

      // build skip tables in parallel
      for (int i = lane; i < 127 * K_; i += 64) {
        const int v = i / K_, j = i - v * K_;
        h2[v][j] = bp[2 * v + 1][bp[2 * v + 2][j]];
      }
      __syncthreads();
      for (int i = lane; i < 63 * K_; i += 64) {
        const int w = i / K_, j = i - w * K_;
        h4[w][j] = h2[2 * w][h2[2 * w + 1][j]];
      }
      __syncthreads();

      if (lane == 0) {
        int cur = last;
        curarr[255] = (unsigned char)cur;
        cur = bp[255][cur]; curarr[254] = (unsigned char)cur;
        cur = h2[126][cur]; curarr[252] = (unsigned char)cur;
        for (int w = 62; w >= 0; --w) {  // 63 dependent u8 reads
          cur = h4[w][cur];
          curarr[4 * w] = (unsigned char)cur;
        }
      }
      __syncthreads();
      if (lane < 63) {  // fill t = 2 mod 4
        const int t = 2 + 4 * lane;
        curarr[t] = h2[t >> 1][curarr[t + 2]];
      }
      __syncthreads();
#pragma unroll
      for (int q = 0; q < 2; ++q) {  // fill odd t
        const int i = q * 64 + lane;
        const int t = 1 + 2 * i;
        if (i < 127) curarr[t] = bp[t + 1][curarr[t + 1]];
      }
      __syncthreads();
#pragma unroll
      for (int q = 0; q < 4; ++q) {
        const int t = q * 64 + lane;
        out_tags[t * B_ + b] = (msk[t] != 0) ? (float)curarr[t] : 0.f;
      }
    }
  } else {
    // ---------------- numerator ----------------
    const int b = blockIdx.x - 2 * B_;
    float contrib = 0.f;
#pragma unroll
    for (int q = 0; q < 4; ++q) {
      const int t = lane * 4 + q;
      const int tg = tags[t * B_ + b];
      const size_t ro = ((size_t)t * B_ + b) * K_;
      if (t == 0) {
        contrib += startT[tg] + P[ro + tg] + P[PR + ro + tg];
      } else if (tg != 0) {
        const int pg = tags[(t - 1) * B_ + b];
        contrib += trans[pg * K_ + tg] + P[ro + tg] + P[PR + ro + tg];
      }
      const bool isLast =
          (tg != 0) && (t == T_ - 1 || tags[(t + 1) * B_ + b] == 0);
      if (isLast) contrib += endT[tg];
    }
#pragma unroll
    for (int off = 32; off > 0; off >>= 1)
      contrib += __shfl_down(contrib, off, 64);
    if (lane == 0) atomicAdd(out_loss, -contrib);  // -num
  }
}

extern "C" void kernel_launch(void* const* d_in, const int* in_sizes, int n_in,
                              void* d_out, int out_size, void* d_ws,
                              size_t ws_size, hipStream_t stream) {
  const float* A = (const float*)d_in[0];
  const int* tags = (const int*)d_in[1];
  const float* W = (const float*)d_in[2];
  const float* bias = (const float*)d_in[3];
  const float* startT = (const float*)d_in[4];
  const float* endT = (const float*)d_in[5];
  const float* trans = (const float*)d_in[6];

  float* out_tags = (float*)d_out;
  float* out_loss = (float*)d_out + (size_t)T_ * B_;
  float* P = (float*)d_ws;  // 2 partial chunks, row layout [t*B+b][k]

  hipMemsetAsync(out_loss, 0, sizeof(float), stream);
  fc_kernel<<<dim3(512, 2), 128, 0, stream>>>(A, W, bias, P);
  scan_kernel<<<3 * B_, 64, 0, stream>>>(P, tags, startT, endT, trans,
                                         out_tags, out_loss);
}

// Round 5
// 318.293 us; speedup vs baseline: 1.5649x; 1.0724x over previous
//
#include <hip/hip_runtime.h>
#include <math.h>

#define T_ 256
#define B_ 128
#define D_ 1024
#define K_ 21
#define NB3 43  // ceil(B_/3) wave-blocks for each scan flavor

typedef short v8s __attribute__((ext_vector_type(8)));
typedef float v4f __attribute__((ext_vector_type(4)));

#define REP21(X) X(0) X(1) X(2) X(3) X(4) X(5) X(6) X(7) X(8) X(9) X(10) \
                 X(11) X(12) X(13) X(14) X(15) X(16) X(17) X(18) X(19) X(20)

__device__ __forceinline__ short bf16rne(float f) {
  unsigned u = __float_as_uint(f);
  u += 0x7FFFu + ((u >> 16) & 1u);  // round-nearest-even
  return (short)(u >> 16);
}
__device__ __forceinline__ float rdl(float v, int l) {
  return __int_as_float(__builtin_amdgcn_readlane(__float_as_int(v), l));
}
__device__ __forceinline__ float bperm(int addr, float v) {
  return __int_as_float(__builtin_amdgcn_ds_bpermute(addr, __float_as_int(v)));
}

// ---------------------------------------------------------------------------
// Kernel 1: FC as bf16 MFMA GEMM. Block = 256 thr (4 waves); wave wv owns
// k-chunk [wv*256, wv*256+256) for rows [blockIdx.x*64, +64) (4 M-tiles of
// 16). B-frags (W) held in registers (16 frags = 64 VGPR), A streamed
// global->reg->bf16 (each element read exactly once: HBM-bound, ~21 us
// floor). Cross-wave k-reduction through LDS; wave 0 adds bias and stores
// the final fc (f32, row = t*B+b, 21 cols).
// ---------------------------------------------------------------------------
__global__ __launch_bounds__(256) void fc_kernel(
    const float* __restrict__ A, const float* __restrict__ W,
    const float* __restrict__ bias, float* __restrict__ fc) {
  __shared__ float red[3][64][22];
  const int lane = threadIdx.x & 63;
  const int wv = threadIdx.x >> 6;
  const int m15 = lane & 15, g4 = lane >> 4;
  const int rowbase = blockIdx.x * 64;
  const int kc = wv * 256;
  const int n1 = 16 + m15;

  // B-frags: B[k][n], n = lane&15 (+16 for tile1), k = kc+32s+8*(lane>>4)+j
  v8s bf[8][2];
#pragma unroll
  for (int s = 0; s < 8; ++s) {
    const float* Wp = W + (size_t)(kc + 32 * s + 8 * g4) * K_;
#pragma unroll
    for (int j = 0; j < 8; ++j) bf[s][0][j] = bf16rne(Wp[j * K_ + m15]);
    if (n1 < K_) {
#pragma unroll
      for (int j = 0; j < 8; ++j) bf[s][1][j] = bf16rne(Wp[j * K_ + n1]);
    } else {
#pragma unroll
      for (int j = 0; j < 8; ++j) bf[s][1][j] = 0;
    }
  }

  v4f acc[4][2];
#pragma unroll
  for (int m = 0; m < 4; ++m) {
    acc[m][0] = (v4f)(0.f);
    acc[m][1] = (v4f)(0.f);
  }

#pragma unroll
  for (int s = 0; s < 8; ++s) {
    v8s av[4];
#pragma unroll
    for (int m = 0; m < 4; ++m) {
      const float* Ap =
          A + (size_t)(rowbase + 16 * m + m15) * D_ + kc + 32 * s + 8 * g4;
      const float4 x = *(const float4*)Ap;
      const float4 y = *(const float4*)(Ap + 4);
      av[m][0] = bf16rne(x.x); av[m][1] = bf16rne(x.y);
      av[m][2] = bf16rne(x.z); av[m][3] = bf16rne(x.w);
      av[m][4] = bf16rne(y.x); av[m][5] = bf16rne(y.y);
      av[m][6] = bf16rne(y.z); av[m][7] = bf16rne(y.w);
    }
#pragma unroll
    for (int m = 0; m < 4; ++m) {
      acc[m][0] = __builtin_amdgcn_mfma_f32_16x16x32_bf16(av[m], bf[s][0],
                                                          acc[m][0], 0, 0, 0);
      acc[m][1] = __builtin_amdgcn_mfma_f32_16x16x32_bf16(av[m], bf[s][1],
                                                          acc[m][1], 0, 0, 0);
    }
  }

  // C/D layout: col = lane&15 (+16 tile1), row_local = 16m + 4*(lane>>4) + ri
  if (wv > 0) {
#pragma unroll
    for (int m = 0; m < 4; ++m)
#pragma unroll
      for (int ri = 0; ri < 4; ++ri) {
        const int rl = 16 * m + 4 * g4 + ri;
        red[wv - 1][rl][m15] = acc[m][0][ri];
        if (n1 < K_) red[wv - 1][rl][n1] = acc[m][1][ri];
      }
  }
  __syncthreads();
  if (wv == 0) {
    const float b0 = bias[m15];
    const float b1 = (n1 < K_) ? bias[n1] : 0.f;
#pragma unroll
    for (int m = 0; m < 4; ++m)
#pragma unroll
      for (int ri = 0; ri < 4; ++ri) {
        const int rl = 16 * m + 4 * g4 + ri;
        float* o = fc + (size_t)(rowbase + rl) * K_;
        o[m15] = acc[m][0][ri] + red[0][rl][m15] + red[1][rl][m15] +
                 red[2][rl][m15] + b0;
        if (n1 < K_)
          o[n1] = acc[m][1][ri] + red[0][rl][n1] + red[1][rl][n1] +
                  red[2][rl][n1] + b1;
      }
  }
}

// ---------------------------------------------------------------------------
// Kernel 2: sequential scans. 3 batches per wave, packed in lanes [0,63):
// lane = g*21 + jloc owns tag-column jloc of batch 3*blk+g. Cross-lane
// matvec via systolic rotation: q[j] = sum_i p[(j+i)%21] * E_rot[i], so the
// 21 ds_bpermutes per step are SHARED by all 3 batches. Mask handled as
// t < len (monotone). Blocks [0,43): forward; [43,86): Viterbi; [86,214):
// numerator (1 batch/block).
// ---------------------------------------------------------------------------
__global__ __launch_bounds__(64) void scan_kernel(
    const float* __restrict__ fc, const int* __restrict__ tags,
    const float* __restrict__ startT, const float* __restrict__ endT,
    const float* __restrict__ trans, float* __restrict__ out_tags,
    float* __restrict__ out_loss) {
  __shared__ unsigned char bp[256 * 66];   // bp[t][g][tag] stride 66/22
  __shared__ unsigned char h2[127 * 66];   // tag@2v   <- tag@(2v+2)
  __shared__ unsigned char h4[63 * 66];    // tag@4w   <- tag@(4w+4)
  __shared__ unsigned char cur[3 * 256];

  const int lane = threadIdx.x;
  const int blk = blockIdx.x;

  if (blk < 2 * NB3) {
    const bool fwd = blk < NB3;
    const int bblk = fwd ? blk : blk - NB3;
    int g = lane / 21;
    if (g > 2) g = 2;
    int jloc = lane - g * 21;
    if (jloc > 20) jloc = 20;
    int batch = bblk * 3 + g;
    if (batch >= B_) batch = B_ - 1;

    // lengths per group (uniform, via ballots); mask[t] == (t < len)
    int len0 = 0, len1 = 0, len2 = 0;
#pragma unroll
    for (int q = 0; q < 4; ++q) {
      const int t = q * 64 + lane;
      int b0 = bblk * 3, b1 = bblk * 3 + 1, b2 = bblk * 3 + 2;
      if (b1 >= B_) b1 = B_ - 1;
      if (b2 >= B_) b2 = B_ - 1;
      len0 += __popcll(__ballot(tags[t * B_ + b0] != 0));
      len1 += __popcll(__ballot(tags[t * B_ + b1] != 0));
      len2 += __popcll(__ballot(tags[t * B_ + b2] != 0));
    }
    const int mylen = (g == 0) ? len0 : (g == 1) ? len1 : len2;

    // rotation constants: src = (jloc+i)%21
    int addr[21];
#pragma unroll
    for (int i = 0; i < K_; ++i) {
      int src = jloc + i;
      if (src >= K_) src -= K_;
      addr[i] = 4 * (g * K_ + src);
    }
    const int addr0 = 4 * (g * K_);  // group's lane-0 (jloc==0)

    const float em0 = fc[(size_t)batch * K_ + jloc];

    if (fwd) {
      // ---------------- forward / denominator (linear domain) ------------
      float et[21];
#pragma unroll
      for (int i = 0; i < K_; ++i) {
        int src = jloc + i;
        if (src >= K_) src -= K_;
        et[i] = __expf(trans[src * K_ + jloc]);
      }
      float p = __expf(startT[jloc] + em0);
      float L = 0.f;
      float vt1 = fc[((size_t)1 * B_ + batch) * K_ + jloc];
      float vt2 = fc[((size_t)2 * B_ + batch) * K_ + jloc];
      float ee = __expf(vt1);

      for (int t = 1; t < T_; ++t) {
        const float eet = ee;
        ee = __expf(vt2);  // exp for t+1, off critical path
        const int tn = (t + 2 < T_) ? t + 2 : T_ - 1;
        vt2 = fc[((size_t)tn * B_ + batch) * K_ + jloc];

        const int pb = __float_as_int(p);
        float d0 = 0.f, d1 = 0.f, d2 = 0.f;
#define FW(i)                                                                \
        {                                                                    \
          const float si = bperm(addr[i], __int_as_float(pb));               \
          if ((i) % 3 == 0) d0 = fmaf(si, et[i], d0);                        \
          else if ((i) % 3 == 1) d1 = fmaf(si, et[i], d1);                   \
          else d2 = fmaf(si, et[i], d2);                                     \
        }
        REP21(FW)
#undef FW
        const float pn = ((d0 + d1) + d2) * eet;
        p = (t < mylen) ? pn : p;
        if ((t & 7) == 0) {  // group-uniform renorm by p[jloc==0] (invariant)
          const float f = bperm(addr0, p);
          p *= __builtin_amdgcn_rcpf(f);
          L += __logf(f);
        }
      }
      const float w = p * __expf(endT[jloc]);
      float res = 0.f;
#pragma unroll
      for (int gg = 0; gg < 3; ++gg) {
        if (bblk * 3 + gg < B_) {
          float tot = 0.f;
#pragma unroll
          for (int i = 0; i < K_; ++i) tot += rdl(w, gg * K_ + i);
          res += rdl(L, gg * K_) + __logf(tot);
        }
      }
      if (lane == 0) atomicAdd(out_loss, res);  // +den
    } else {
      // ---------------- Viterbi ----------------
      float tr[21];
      int enc[21];
#pragma unroll
      for (int i = 0; i < K_; ++i) {
        int src = jloc + i;
        if (src >= K_) src -= K_;
        tr[i] = trans[src * K_ + jloc] + 2048.0f;
        enc[i] = 20 - src;  // larger key <=> smaller prev tag (first-argmax)
      }
      float sc = startT[jloc] + em0;
      float vt1 = fc[((size_t)1 * B_ + batch) * K_ + jloc];
      float vt2 = fc[((size_t)2 * B_ + batch) * K_ + jloc];

      for (int t = 1; t < T_; ++t) {
        const float emt = vt1;
        vt1 = vt2;
        const int tn = (t + 2 < T_) ? t + 2 : T_ - 1;
        vt2 = fc[((size_t)tn * B_ + batch) * K_ + jloc];

        const int sb = __float_as_int(sc);
        int k0 = 0, k1 = 0, k2 = 0;  // keys positive (score+2048 > 0)
#define VT(i)                                                                \
        {                                                                    \
          const float si = bperm(addr[i], __int_as_float(sb));               \
          const float c = si + tr[i];                                        \
          const int kk = (__float_as_int(c) & 0xFFFFFFE0) | enc[i];          \
          if ((i) % 3 == 0) k0 = k0 > kk ? k0 : kk;                          \
          else if ((i) % 3 == 1) k1 = k1 > kk ? k1 : kk;                     \
          else k2 = k2 > kk ? k2 : kk;                                       \
        }
        REP21(VT)
#undef VT
        int km = k0 > k1 ? k0 : k1;
        km = km > k2 ? km : k2;
        const float nxt = __int_as_float(km & 0xFFFFFFE0) - 2048.0f + emt;
        const bool m = t < mylen;
        sc = m ? nxt : sc;
        const int pw = m ? (20 - (km & 31)) : jloc;  // identity when frozen
        if (lane < 63) bp[t * 66 + g * 22 + jloc] = (unsigned char)pw;
      }
      __syncthreads();

      // final argmax per group (tie-break: smallest tag)
      const float finb = sc + endT[jloc] + 2048.0f;
      const int myk = (__float_as_int(finb) & 0xFFFFFFE0) | (20 - jloc);
      int last0 = 0, last1 = 0, last2 = 0;
#pragma unroll
      for (int gg = 0; gg < 3; ++gg) {
        int km = 0;
#pragma unroll
        for (int i = 0; i < K_; ++i) {
          const int ki = __builtin_amdgcn_readlane(myk, gg * K_ + i);
          km = km > ki ? km : ki;
        }
        const int lt = 20 - (km & 31);
        if (gg == 0) last0 = lt;
        else if (gg == 1) last1 = lt;
        else last2 = lt;
      }

      // skip tables (parallel over lanes)
      for (int i = lane; i < 127 * 63; i += 64) {
        const int v = i / 63;
        const int rem = i - v * 63;
        const int gg = rem / 21, j = rem - (rem / 21) * 21;
        h2[v * 66 + gg * 22 + j] =
            bp[(2 * v + 1) * 66 + gg * 22 + bp[(2 * v + 2) * 66 + gg * 22 + j]];
      }
      __syncthreads();
      for (int i = lane; i < 63 * 63; i += 64) {
        const int w = i / 63;
        const int rem = i - w * 63;
        const int gg = rem / 21, j = rem - (rem / 21) * 21;
        h4[w * 66 + gg * 22 + j] =
            h2[(2 * w) * 66 + gg * 22 + h2[(2 * w + 1) * 66 + gg * 22 + j]];
      }
      __syncthreads();

      // 3 parallel serial chases (lane == group)
      if (lane < 3 && bblk * 3 + lane < B_) {
        int c = (lane == 0) ? last0 : (lane == 1) ? last1 : last2;
        cur[lane * 256 + 255] = (unsigned char)c;
        c = bp[255 * 66 + lane * 22 + c];
        cur[lane * 256 + 254] = (unsigned char)c;
        c = h2[126 * 66 + lane * 22 + c];
        cur[lane * 256 + 252] = (unsigned char)c;
        for (int w = 62; w >= 0; --w) {
          c = h4[w * 66 + lane * 22 + c];
          cur[lane * 256 + 4 * w] = (unsigned char)c;
        }
      }
      __syncthreads();
      for (int i = lane; i < 63 * 3; i += 64) {  // t = 2 mod 4
        const int gg = i / 63, ii = i - (i / 63) * 63;
        const int t = 2 + 4 * ii;
        cur[gg * 256 + t] =
            h2[(t >> 1) * 66 + gg * 22 + cur[gg * 256 + t + 2]];
      }
      __syncthreads();
      for (int i = lane; i < 127 * 3; i += 64) {  // odd t
        const int gg = i / 127, ii = i - (i / 127) * 127;
        const int t = 1 + 2 * ii;
        cur[gg * 256 + t] =
            bp[(t + 1) * 66 + gg * 22 + cur[gg * 256 + t + 1]];
      }
      __syncthreads();
      for (int i = lane; i < 3 * 256; i += 64) {
        const int gg = i >> 8, t = i & 255;
        const int bb = bblk * 3 + gg;
        const int lg = (gg == 0) ? len0 : (gg == 1) ? len1 : len2;
        if (bb < B_)
          out_tags[t * B_ + bb] = (t < lg) ? (float)cur[gg * 256 + t] : 0.f;
      }
    }
  } else {
    // ---------------- numerator ----------------
    const int b = blk - 2 * NB3;
    float contrib = 0.f;
#pragma unroll
    for (int q = 0; q < 4; ++q) {
      const int t = lane * 4 + q;
      const int tg = tags[t * B_ + b];
      const size_t ro = ((size_t)t * B_ + b) * K_;
      if (t == 0) {
        contrib += startT[tg] + fc[ro + tg];
      } else if (tg != 0) {
        const int pg = tags[(t - 1) * B_ + b];
        contrib += trans[pg * K_ + tg] + fc[ro + tg];
      }
      const bool isLast =
          (tg != 0) && (t == T_ - 1 || tags[(t + 1) * B_ + b] == 0);
      if (isLast) contrib += endT[tg];
    }
#pragma unroll
    for (int off = 32; off > 0; off >>= 1)
      contrib += __shfl_down(contrib, off, 64);
    if (lane == 0) atomicAdd(out_loss, -contrib);  // -num
  }
}

extern "C" void kernel_launch(void* const* d_in, const int* in_sizes, int n_in,
                              void* d_out, int out_size, void* d_ws,
                              size_t ws_size, hipStream_t stream) {
  const float* A = (const float*)d_in[0];
  const int* tags = (const int*)d_in[1];
  const float* W = (const float*)d_in[2];
  const float* bias = (const float*)d_in[3];
  const float* startT = (const float*)d_in[4];
  const float* endT = (const float*)d_in[5];
  const float* trans = (const float*)d_in[6];

  float* out_tags = (float*)d_out;
  float* out_loss = (float*)d_out + (size_t)T_ * B_;
  float* fc = (float*)d_ws;  // [t*B+b][21] f32, 2.75 MB

  hipMemsetAsync(out_loss, 0, sizeof(float), stream);
  fc_kernel<<<512, 256, 0, stream>>>(A, W, bias, fc);
  scan_kernel<<<2 * NB3 + B_, 64, 0, stream>>>(fc, tags, startT, endT, trans,
                                               out_tags, out_loss);
}